// Round 1
// baseline (1072.733 us; speedup 1.0000x reference)
//
#include <hip/hip_runtime.h>
#include <hip/hip_bf16.h>

// Problem constants
constexpr int kL  = 2048;   // sequence length
constexpr int kD  = 64;     // head dim
constexpr int kBH = 64;     // B*H = 4*16
constexpr size_t kAttnOff = (size_t)4 * 16 * 2048 * 64 * 2;  // output elems before attn

typedef __bf16 bf16x8 __attribute__((ext_vector_type(8)));
typedef __bf16 bf16x2 __attribute__((ext_vector_type(2)));
typedef float  f32x4  __attribute__((ext_vector_type(4)));

// ---------------------------------------------------------------------------
// Kernel A: scores -> e = exp(|s|/8), write e to attn buffer, rowsums to ws.
// Block: 256 threads (4 waves). Each wave owns 16 q-rows; block owns 64 q-rows.
// K staged in LDS as bf16 [64 rows][64 d], XOR-swizzled (byte ^= (row&7)<<4).
// MFMA 16x16x32 bf16: A-frag a[i]=A[lane&15][(lane>>4)*8+i],
//                     B-frag b[i]=B[(lane>>4)*8+i][lane&15],
//                     D d[i]=D[(lane>>4)*4+i][lane&15]  (verified layouts)
// ---------------------------------------------------------------------------
__global__ __launch_bounds__(256) void qk_exp_kernel(
    const float* __restrict__ qr_g, const float* __restrict__ qi_g,
    const float* __restrict__ kr_g, const float* __restrict__ ki_g,
    float* __restrict__ attn, float* __restrict__ rowsum)
{
  __shared__ __align__(16) char lds_raw[2 * 64 * 128];
  char* kr_l = lds_raw;
  char* ki_l = lds_raw + 64 * 128;

  const int tid  = threadIdx.x;
  const int wave = tid >> 6;
  const int lane = tid & 63;
  const int g    = lane >> 4;   // 0..3
  const int r    = lane & 15;   // 0..15
  const int bh   = blockIdx.y;
  const int q0   = blockIdx.x * 64 + wave * 16;

  // Load Q fragments (q rows q0..q0+15, all 64 d) into registers, bf16.
  bf16x8 aqr[2], aqi[2], aqrn[2];
  {
    const size_t qbase = ((size_t)bh * kL + q0 + r) * kD + g * 8;
    const float* qrp = qr_g + qbase;
    const float* qip = qi_g + qbase;
#pragma unroll
    for (int f = 0; f < 2; ++f) {
      float4 x0 = *(const float4*)(qrp + f * 32);
      float4 x1 = *(const float4*)(qrp + f * 32 + 4);
      float4 y0 = *(const float4*)(qip + f * 32);
      float4 y1 = *(const float4*)(qip + f * 32 + 4);
      float xr[8] = {x0.x, x0.y, x0.z, x0.w, x1.x, x1.y, x1.z, x1.w};
      float xi[8] = {y0.x, y0.y, y0.z, y0.w, y1.x, y1.y, y1.z, y1.w};
#pragma unroll
      for (int i = 0; i < 8; ++i) {
        aqr[f][i]  = (__bf16)xr[i];
        aqrn[f][i] = (__bf16)(-xr[i]);
        aqi[f][i]  = (__bf16)xi[i];
      }
    }
  }

  float rs[4] = {0.f, 0.f, 0.f, 0.f};

  for (int k0 = 0; k0 < kL; k0 += 64) {
    __syncthreads();
    // Stage K chunk [64 k][64 d] (real+imag) as swizzled bf16.
    {
      const int row = tid >> 2;
      const int d0  = (tid & 3) << 4;
      const size_t gb = ((size_t)bh * kL + k0 + row) * kD + d0;
      const int base = row * 128 + d0 * 2;
      const int swz  = (row & 7) << 4;
      {
        float4 x0 = *(const float4*)(kr_g + gb);
        float4 x1 = *(const float4*)(kr_g + gb + 4);
        float4 x2 = *(const float4*)(kr_g + gb + 8);
        float4 x3 = *(const float4*)(kr_g + gb + 12);
        bf16x8 p0, p1;
        p0[0]=(__bf16)x0.x; p0[1]=(__bf16)x0.y; p0[2]=(__bf16)x0.z; p0[3]=(__bf16)x0.w;
        p0[4]=(__bf16)x1.x; p0[5]=(__bf16)x1.y; p0[6]=(__bf16)x1.z; p0[7]=(__bf16)x1.w;
        p1[0]=(__bf16)x2.x; p1[1]=(__bf16)x2.y; p1[2]=(__bf16)x2.z; p1[3]=(__bf16)x2.w;
        p1[4]=(__bf16)x3.x; p1[5]=(__bf16)x3.y; p1[6]=(__bf16)x3.z; p1[7]=(__bf16)x3.w;
        *(bf16x8*)(kr_l + (base ^ swz))        = p0;
        *(bf16x8*)(kr_l + ((base + 16) ^ swz)) = p1;
      }
      {
        float4 x0 = *(const float4*)(ki_g + gb);
        float4 x1 = *(const float4*)(ki_g + gb + 4);
        float4 x2 = *(const float4*)(ki_g + gb + 8);
        float4 x3 = *(const float4*)(ki_g + gb + 12);
        bf16x8 p0, p1;
        p0[0]=(__bf16)x0.x; p0[1]=(__bf16)x0.y; p0[2]=(__bf16)x0.z; p0[3]=(__bf16)x0.w;
        p0[4]=(__bf16)x1.x; p0[5]=(__bf16)x1.y; p0[6]=(__bf16)x1.z; p0[7]=(__bf16)x1.w;
        p1[0]=(__bf16)x2.x; p1[1]=(__bf16)x2.y; p1[2]=(__bf16)x2.z; p1[3]=(__bf16)x2.w;
        p1[4]=(__bf16)x3.x; p1[5]=(__bf16)x3.y; p1[6]=(__bf16)x3.z; p1[7]=(__bf16)x3.w;
        *(bf16x8*)(ki_l + (base ^ swz))        = p0;
        *(bf16x8*)(ki_l + ((base + 16) ^ swz)) = p1;
      }
    }
    __syncthreads();

#pragma unroll
    for (int s = 0; s < 4; ++s) {
      const int krow = s * 16 + r;     // B-frag column r comes from K row krow
      const int swz  = (krow & 7) << 4;
      f32x4 accr = {0.f, 0.f, 0.f, 0.f};
      f32x4 acci = {0.f, 0.f, 0.f, 0.f};
#pragma unroll
      for (int f = 0; f < 2; ++f) {
        const int byte = (krow * 128 + (f * 32 + g * 8) * 2) ^ swz;
        bf16x8 bkr = *(const bf16x8*)(kr_l + byte);
        bf16x8 bki = *(const bf16x8*)(ki_l + byte);
        accr = __builtin_amdgcn_mfma_f32_16x16x32_bf16(aqr[f],  bkr, accr, 0, 0, 0);
        accr = __builtin_amdgcn_mfma_f32_16x16x32_bf16(aqi[f],  bki, accr, 0, 0, 0);
        acci = __builtin_amdgcn_mfma_f32_16x16x32_bf16(aqi[f],  bkr, acci, 0, 0, 0);
        acci = __builtin_amdgcn_mfma_f32_16x16x32_bf16(aqrn[f], bki, acci, 0, 0, 0);
      }
      const int kglob = k0 + s * 16 + r;
      const size_t abase = ((size_t)bh * kL + (q0 + g * 4)) * kL + kglob;
#pragma unroll
      for (int i = 0; i < 4; ++i) {
        float sr = accr[i] * 0.125f;
        float si = acci[i] * 0.125f;
        float e  = __expf(sqrtf(sr * sr + si * si));
        rs[i] += e;
        attn[abase + (size_t)i * kL] = e;
      }
    }
  }

  // Reduce rowsums across the 16 lanes of each group (same lane>>4).
#pragma unroll
  for (int m = 1; m < 16; m <<= 1) {
#pragma unroll
    for (int i = 0; i < 4; ++i) rs[i] += __shfl_xor(rs[i], m, 64);
  }
  if (r == 0) {
#pragma unroll
    for (int i = 0; i < 4; ++i)
      rowsum[(size_t)bh * kL + q0 + g * 4 + i] = rs[i];
  }
}

// ---------------------------------------------------------------------------
// Kernel B: normalize attn in-place and compute out = attn @ V (real & imag).
// Block: 256 threads (4 waves); block owns 64 q-rows, all 64 d output cols.
// V chunk [64 k][64 d] staged TRANSPOSED in LDS as bf16 VT[d][k], swizzled.
// ---------------------------------------------------------------------------
__global__ __launch_bounds__(256) void pv_kernel(
    const float* __restrict__ vr_g, const float* __restrict__ vi_g,
    float* __restrict__ attn, const float* __restrict__ rowsum,
    float* __restrict__ out)
{
  __shared__ __align__(16) char lds_raw[2 * 64 * 128];
  char* vr_l = lds_raw;
  char* vi_l = lds_raw + 64 * 128;

  const int tid  = threadIdx.x;
  const int wave = tid >> 6;
  const int lane = tid & 63;
  const int g    = lane >> 4;
  const int r    = lane & 15;
  const int bh   = blockIdx.y;
  const int q0   = blockIdx.x * 64 + wave * 16;

  const float inv = 1.0f / rowsum[(size_t)bh * kL + q0 + r];

  f32x4 o_r[4], o_i[4];
#pragma unroll
  for (int dt = 0; dt < 4; ++dt) {
    o_r[dt] = (f32x4){0.f, 0.f, 0.f, 0.f};
    o_i[dt] = (f32x4){0.f, 0.f, 0.f, 0.f};
  }

  for (int k0 = 0; k0 < kL; k0 += 64) {
    __syncthreads();
    // Stage V^T chunk: VT[d][k] bf16, swizzled byte ^= (d&7)<<4.
    {
      const int p  = tid >> 3;         // k-pair index 0..31
      const int d0 = (tid & 7) << 3;   // 0..56
      const size_t gb0 = ((size_t)bh * kL + k0 + 2 * p) * kD + d0;
      const size_t gb1 = gb0 + kD;
      float4 a0 = *(const float4*)(vr_g + gb0);
      float4 a1 = *(const float4*)(vr_g + gb0 + 4);
      float4 a2 = *(const float4*)(vr_g + gb1);
      float4 a3 = *(const float4*)(vr_g + gb1 + 4);
      float4 b0 = *(const float4*)(vi_g + gb0);
      float4 b1 = *(const float4*)(vi_g + gb0 + 4);
      float4 b2 = *(const float4*)(vi_g + gb1);
      float4 b3 = *(const float4*)(vi_g + gb1 + 4);
      float vr0[8] = {a0.x, a0.y, a0.z, a0.w, a1.x, a1.y, a1.z, a1.w};
      float vr1[8] = {a2.x, a2.y, a2.z, a2.w, a3.x, a3.y, a3.z, a3.w};
      float vi0[8] = {b0.x, b0.y, b0.z, b0.w, b1.x, b1.y, b1.z, b1.w};
      float vi1[8] = {b2.x, b2.y, b2.z, b2.w, b3.x, b3.y, b3.z, b3.w};
#pragma unroll
      for (int j = 0; j < 8; ++j) {
        const int d = d0 + j;
        const int byte = (d * 128 + p * 4) ^ ((d & 7) << 4);
        bf16x2 pa; pa[0] = (__bf16)vr0[j]; pa[1] = (__bf16)vr1[j];
        *(bf16x2*)(vr_l + byte) = pa;
        bf16x2 pb; pb[0] = (__bf16)vi0[j]; pb[1] = (__bf16)vi1[j];
        *(bf16x2*)(vi_l + byte) = pb;
      }
    }
    __syncthreads();

#pragma unroll
    for (int kh = 0; kh < 2; ++kh) {
      // A-frag: normalized attn row q0+r, k = k0 + kh*32 + g*8 .. +7
      const size_t ab = ((size_t)bh * kL + q0 + r) * kL + k0 + kh * 32 + g * 8;
      float4 e0 = *(const float4*)(attn + ab);
      float4 e1 = *(const float4*)(attn + ab + 4);
      float n[8] = {e0.x * inv, e0.y * inv, e0.z * inv, e0.w * inv,
                    e1.x * inv, e1.y * inv, e1.z * inv, e1.w * inv};
      float4 w0 = {n[0], n[1], n[2], n[3]};
      float4 w1 = {n[4], n[5], n[6], n[7]};
      *(float4*)(attn + ab)     = w0;   // write back normalized attn
      *(float4*)(attn + ab + 4) = w1;
      bf16x8 af;
#pragma unroll
      for (int j = 0; j < 8; ++j) af[j] = (__bf16)n[j];

#pragma unroll
      for (int dt = 0; dt < 4; ++dt) {
        const int d = dt * 16 + r;
        const int byte = (d * 128 + (kh * 32 + g * 8) * 2) ^ ((d & 7) << 4);
        bf16x8 bvr = *(const bf16x8*)(vr_l + byte);
        bf16x8 bvi = *(const bf16x8*)(vi_l + byte);
        o_r[dt] = __builtin_amdgcn_mfma_f32_16x16x32_bf16(af, bvr, o_r[dt], 0, 0, 0);
        o_i[dt] = __builtin_amdgcn_mfma_f32_16x16x32_bf16(af, bvi, o_i[dt], 0, 0, 0);
      }
    }
  }

  // Write output: [bh, q, d, 2] with (real, imag) interleaved -> float2 stores.
#pragma unroll
  for (int dt = 0; dt < 4; ++dt) {
#pragma unroll
    for (int i = 0; i < 4; ++i) {
      const size_t q = q0 + g * 4 + i;
      const int d = dt * 16 + r;
      float2 val;
      val.x = o_r[dt][i];
      val.y = o_i[dt][i];
      *(float2*)(out + (((size_t)bh * kL + q) * kD + d) * 2) = val;
    }
  }
}

extern "C" void kernel_launch(void* const* d_in, const int* in_sizes, int n_in,
                              void* d_out, int out_size, void* d_ws, size_t ws_size,
                              hipStream_t stream) {
  const float* qr = (const float*)d_in[0];
  const float* qi = (const float*)d_in[1];
  const float* kr = (const float*)d_in[2];
  const float* ki = (const float*)d_in[3];
  const float* vr = (const float*)d_in[4];
  const float* vi = (const float*)d_in[5];
  float* out  = (float*)d_out;
  float* attn = out + kAttnOff;
  float* rowsum = (float*)d_ws;   // kBH*kL floats = 512 KB

  dim3 grid(kL / 64, kBH);
  qk_exp_kernel<<<grid, 256, 0, stream>>>(qr, qi, kr, ki, attn, rowsum);
  pv_kernel<<<grid, 256, 0, stream>>>(vr, vi, attn, rowsum, out);
}

// Round 2
// 865.581 us; speedup vs baseline: 1.2393x; 1.2393x over previous
//
#include <hip/hip_runtime.h>
#include <hip/hip_bf16.h>

// Problem constants
constexpr int kL  = 2048;   // sequence length
constexpr int kD  = 64;     // head dim
constexpr int kBH = 64;     // B*H = 4*16
constexpr size_t kAttnOff = (size_t)kBH * kL * kD * 2;  // output elems before attn

typedef __bf16 bf16x8 __attribute__((ext_vector_type(8)));
typedef __bf16 bf16x4 __attribute__((ext_vector_type(4)));
typedef __bf16 bf16x2 __attribute__((ext_vector_type(2)));
typedef float  f32x4  __attribute__((ext_vector_type(4)));
typedef unsigned int u32x4 __attribute__((ext_vector_type(4)));

static __device__ inline bf16x8 neg8(bf16x8 v) {
  u32x4 t = __builtin_bit_cast(u32x4, v);
  t ^= 0x80008000u;
  return __builtin_bit_cast(bf16x8, t);
}

// ---------------------------------------------------------------------------
// Kernel A: e = exp(|<q/8, conj(k)>|), rowsums.
// Block: 256 thr / 4 waves, owns 256 q-rows (64 per wave as 4 q-tiles of 16).
// K chunk [64 k][64 d] staged in LDS bf16, XOR-swizzled (byte ^= (row&7)<<4).
// Swapped MFMA: D[k][q] = mfma(K_frag, Q_frag)  ->  lane holds 4 consecutive k
// for q = qtile_base + (lane&15). Stores e as bf16 (ws) or f32 (attn fallback).
// MFMA 16x16x32 bf16 layouts: a[i]=A[lane&15][(lane>>4)*8+i],
//   b[i]=B[(lane>>4)*8+i][lane&15], d[i]=D[(lane>>4)*4+i][lane&15].
// ---------------------------------------------------------------------------
template<int WS>
__global__ __launch_bounds__(256) void qk_exp_kernel(
    const float* __restrict__ qr_g, const float* __restrict__ qi_g,
    const float* __restrict__ kr_g, const float* __restrict__ ki_g,
    __hip_bfloat16* __restrict__ ews, float* __restrict__ attn,
    float* __restrict__ rowsum)
{
  __shared__ __align__(16) char lds_raw[2 * 64 * 128];   // 16 KB
  char* kr_l = lds_raw;
  char* ki_l = lds_raw + 64 * 128;

  const int tid  = threadIdx.x;
  const int wave = tid >> 6;
  const int lane = tid & 63;
  const int g    = lane >> 4;   // 0..3
  const int r    = lane & 15;   // 0..15
  const int bh   = blockIdx.y;
  const int q0w  = blockIdx.x * 256 + wave * 64;   // wave's q base (4 tiles)

  // Q fragments, scaled by 1/8 (temperature), bf16. 64 VGPRs.
  bf16x8 aqr[4][2], aqi[4][2];
#pragma unroll
  for (int qt = 0; qt < 4; ++qt) {
    const size_t qbase = ((size_t)bh * kL + q0w + qt * 16 + r) * kD + g * 8;
#pragma unroll
    for (int f = 0; f < 2; ++f) {
      float4 x0 = *(const float4*)(qr_g + qbase + f * 32);
      float4 x1 = *(const float4*)(qr_g + qbase + f * 32 + 4);
      float4 y0 = *(const float4*)(qi_g + qbase + f * 32);
      float4 y1 = *(const float4*)(qi_g + qbase + f * 32 + 4);
      float xr[8] = {x0.x, x0.y, x0.z, x0.w, x1.x, x1.y, x1.z, x1.w};
      float xi[8] = {y0.x, y0.y, y0.z, y0.w, y1.x, y1.y, y1.z, y1.w};
#pragma unroll
      for (int i = 0; i < 8; ++i) {
        aqr[qt][f][i] = (__bf16)(xr[i] * 0.125f);
        aqi[qt][f][i] = (__bf16)(xi[i] * 0.125f);
      }
    }
  }

  float rs[4] = {0.f, 0.f, 0.f, 0.f};

  for (int k0 = 0; k0 < kL; k0 += 64) {
    __syncthreads();
    // Stage K chunk [64 k][64 d] (real+imag), swizzled bf16.
    {
      const int row = tid >> 2;
      const int d0  = (tid & 3) << 4;
      const size_t gb = ((size_t)bh * kL + k0 + row) * kD + d0;
      const int base = row * 128 + d0 * 2;
      const int swz  = (row & 7) << 4;
      {
        float4 x0 = *(const float4*)(kr_g + gb);
        float4 x1 = *(const float4*)(kr_g + gb + 4);
        float4 x2 = *(const float4*)(kr_g + gb + 8);
        float4 x3 = *(const float4*)(kr_g + gb + 12);
        bf16x8 p0, p1;
        p0[0]=(__bf16)x0.x; p0[1]=(__bf16)x0.y; p0[2]=(__bf16)x0.z; p0[3]=(__bf16)x0.w;
        p0[4]=(__bf16)x1.x; p0[5]=(__bf16)x1.y; p0[6]=(__bf16)x1.z; p0[7]=(__bf16)x1.w;
        p1[0]=(__bf16)x2.x; p1[1]=(__bf16)x2.y; p1[2]=(__bf16)x2.z; p1[3]=(__bf16)x2.w;
        p1[4]=(__bf16)x3.x; p1[5]=(__bf16)x3.y; p1[6]=(__bf16)x3.z; p1[7]=(__bf16)x3.w;
        *(bf16x8*)(kr_l + (base ^ swz))        = p0;
        *(bf16x8*)(kr_l + ((base + 16) ^ swz)) = p1;
      }
      {
        float4 x0 = *(const float4*)(ki_g + gb);
        float4 x1 = *(const float4*)(ki_g + gb + 4);
        float4 x2 = *(const float4*)(ki_g + gb + 8);
        float4 x3 = *(const float4*)(ki_g + gb + 12);
        bf16x8 p0, p1;
        p0[0]=(__bf16)x0.x; p0[1]=(__bf16)x0.y; p0[2]=(__bf16)x0.z; p0[3]=(__bf16)x0.w;
        p0[4]=(__bf16)x1.x; p0[5]=(__bf16)x1.y; p0[6]=(__bf16)x1.z; p0[7]=(__bf16)x1.w;
        p1[0]=(__bf16)x2.x; p1[1]=(__bf16)x2.y; p1[2]=(__bf16)x2.z; p1[3]=(__bf16)x2.w;
        p1[4]=(__bf16)x3.x; p1[5]=(__bf16)x3.y; p1[6]=(__bf16)x3.z; p1[7]=(__bf16)x3.w;
        *(bf16x8*)(ki_l + (base ^ swz))        = p0;
        *(bf16x8*)(ki_l + ((base + 16) ^ swz)) = p1;
      }
    }
    __syncthreads();

#pragma unroll
    for (int s = 0; s < 4; ++s) {
      const int krow = s * 16 + r;
      const int swz  = (krow & 7) << 4;
      bf16x8 bkr[2], bki[2], bkin[2];
#pragma unroll
      for (int f = 0; f < 2; ++f) {
        const int byte = (krow * 128 + (f * 32 + g * 8) * 2) ^ swz;
        bkr[f]  = *(const bf16x8*)(kr_l + byte);
        bki[f]  = *(const bf16x8*)(ki_l + byte);
        bkin[f] = neg8(bki[f]);
      }
#pragma unroll
      for (int qt = 0; qt < 4; ++qt) {
        f32x4 accr = {0.f, 0.f, 0.f, 0.f};
        f32x4 acci = {0.f, 0.f, 0.f, 0.f};
#pragma unroll
        for (int f = 0; f < 2; ++f) {
          accr = __builtin_amdgcn_mfma_f32_16x16x32_bf16(bkr[f],  aqr[qt][f], accr, 0, 0, 0);
          accr = __builtin_amdgcn_mfma_f32_16x16x32_bf16(bki[f],  aqi[qt][f], accr, 0, 0, 0);
          acci = __builtin_amdgcn_mfma_f32_16x16x32_bf16(bkr[f],  aqi[qt][f], acci, 0, 0, 0);
          acci = __builtin_amdgcn_mfma_f32_16x16x32_bf16(bkin[f], aqr[qt][f], acci, 0, 0, 0);
        }
        float e[4];
#pragma unroll
        for (int i = 0; i < 4; ++i)
          e[i] = __expf(sqrtf(accr[i] * accr[i] + acci[i] * acci[i]));
        rs[qt] += (e[0] + e[1]) + (e[2] + e[3]);
        const size_t q = q0w + qt * 16 + r;
        const size_t base = ((size_t)bh * kL + q) * kL + k0 + s * 16 + g * 4;
        if (WS) {
          bf16x4 pe;
#pragma unroll
          for (int i = 0; i < 4; ++i) pe[i] = (__bf16)e[i];
          *(bf16x4*)((__bf16*)ews + base) = pe;
        } else {
          float4 pe = {e[0], e[1], e[2], e[3]};
          *(float4*)(attn + base) = pe;
        }
      }
    }
  }

  // Reduce rowsums over the 4 k-quadrant groups (g).
#pragma unroll
  for (int qt = 0; qt < 4; ++qt) {
    rs[qt] += __shfl_xor(rs[qt], 16, 64);
    rs[qt] += __shfl_xor(rs[qt], 32, 64);
  }
  if (lane < 16) {
#pragma unroll
    for (int qt = 0; qt < 4; ++qt)
      rowsum[(size_t)bh * kL + q0w + qt * 16 + lane] = rs[qt];
  }
}

// ---------------------------------------------------------------------------
// Kernel B: write normalized attn (f32) and out = (e @ V) * inv (real & imag).
// Block: 256 thr / 4 waves, owns 128 q-rows (32 per wave as 2 q-tiles).
// V chunk [64 k][64 d] staged TRANSPOSED in LDS bf16 VT[d][k], swizzled.
// MFMA consumes RAW e (bf16); 1/rowsum applied at attn-write and out-epilogue.
// ---------------------------------------------------------------------------
template<int WS>
__global__ __launch_bounds__(256) void pv_kernel(
    const float* __restrict__ vr_g, const float* __restrict__ vi_g,
    const __hip_bfloat16* __restrict__ ews, float* __restrict__ attn,
    const float* __restrict__ rowsum, float* __restrict__ out)
{
  __shared__ __align__(16) char lds_raw[2 * 64 * 128];   // 16 KB
  char* vr_l = lds_raw;
  char* vi_l = lds_raw + 64 * 128;

  const int tid  = threadIdx.x;
  const int wave = tid >> 6;
  const int lane = tid & 63;
  const int g    = lane >> 4;
  const int r    = lane & 15;
  const int bh   = blockIdx.y;
  const int q0w  = blockIdx.x * 128 + wave * 32;   // wave's q base (2 tiles)

  float invA[2];
#pragma unroll
  for (int qt = 0; qt < 2; ++qt)
    invA[qt] = 1.0f / rowsum[(size_t)bh * kL + q0w + qt * 16 + r];

  f32x4 o_r[2][4], o_i[2][4];
#pragma unroll
  for (int qt = 0; qt < 2; ++qt)
#pragma unroll
    for (int dt = 0; dt < 4; ++dt) {
      o_r[qt][dt] = (f32x4){0.f, 0.f, 0.f, 0.f};
      o_i[qt][dt] = (f32x4){0.f, 0.f, 0.f, 0.f};
    }

  for (int k0 = 0; k0 < kL; k0 += 64) {
    __syncthreads();
    // Stage V^T chunk: VT[d][k] bf16, swizzled byte ^= (d&7)<<4.
    {
      const int p  = tid >> 3;         // k-pair 0..31
      const int d0 = (tid & 7) << 3;   // 0..56
      const size_t gb0 = ((size_t)bh * kL + k0 + 2 * p) * kD + d0;
      const size_t gb1 = gb0 + kD;
      float4 a0 = *(const float4*)(vr_g + gb0);
      float4 a1 = *(const float4*)(vr_g + gb0 + 4);
      float4 a2 = *(const float4*)(vr_g + gb1);
      float4 a3 = *(const float4*)(vr_g + gb1 + 4);
      float4 b0 = *(const float4*)(vi_g + gb0);
      float4 b1 = *(const float4*)(vi_g + gb0 + 4);
      float4 b2 = *(const float4*)(vi_g + gb1);
      float4 b3 = *(const float4*)(vi_g + gb1 + 4);
      float vr0[8] = {a0.x, a0.y, a0.z, a0.w, a1.x, a1.y, a1.z, a1.w};
      float vr1[8] = {a2.x, a2.y, a2.z, a2.w, a3.x, a3.y, a3.z, a3.w};
      float vi0[8] = {b0.x, b0.y, b0.z, b0.w, b1.x, b1.y, b1.z, b1.w};
      float vi1[8] = {b2.x, b2.y, b2.z, b2.w, b3.x, b3.y, b3.z, b3.w};
#pragma unroll
      for (int j = 0; j < 8; ++j) {
        const int d = d0 + j;
        const int byte = (d * 128 + p * 4) ^ ((d & 7) << 4);
        bf16x2 pa; pa[0] = (__bf16)vr0[j]; pa[1] = (__bf16)vr1[j];
        *(bf16x2*)(vr_l + byte) = pa;
        bf16x2 pb; pb[0] = (__bf16)vi0[j]; pb[1] = (__bf16)vi1[j];
        *(bf16x2*)(vi_l + byte) = pb;
      }
    }
    __syncthreads();

#pragma unroll
    for (int kh = 0; kh < 2; ++kh) {
      bf16x8 af[2];
#pragma unroll
      for (int qt = 0; qt < 2; ++qt) {
        const size_t q = q0w + qt * 16 + r;
        const size_t eb = ((size_t)bh * kL + q) * kL + k0 + kh * 32 + g * 8;
        if (WS) {
          af[qt] = *(const bf16x8*)((const __bf16*)ews + eb);
          // normalized attn write
          float4 w0, w1;
          w0.x = (float)af[qt][0] * invA[qt]; w0.y = (float)af[qt][1] * invA[qt];
          w0.z = (float)af[qt][2] * invA[qt]; w0.w = (float)af[qt][3] * invA[qt];
          w1.x = (float)af[qt][4] * invA[qt]; w1.y = (float)af[qt][5] * invA[qt];
          w1.z = (float)af[qt][6] * invA[qt]; w1.w = (float)af[qt][7] * invA[qt];
          *(float4*)(attn + eb)     = w0;
          *(float4*)(attn + eb + 4) = w1;
        } else {
          float4 e0 = *(const float4*)(attn + eb);
          float4 e1 = *(const float4*)(attn + eb + 4);
          af[qt][0]=(__bf16)e0.x; af[qt][1]=(__bf16)e0.y; af[qt][2]=(__bf16)e0.z; af[qt][3]=(__bf16)e0.w;
          af[qt][4]=(__bf16)e1.x; af[qt][5]=(__bf16)e1.y; af[qt][6]=(__bf16)e1.z; af[qt][7]=(__bf16)e1.w;
          float4 w0 = {e0.x * invA[qt], e0.y * invA[qt], e0.z * invA[qt], e0.w * invA[qt]};
          float4 w1 = {e1.x * invA[qt], e1.y * invA[qt], e1.z * invA[qt], e1.w * invA[qt]};
          *(float4*)(attn + eb)     = w0;
          *(float4*)(attn + eb + 4) = w1;
        }
      }
#pragma unroll
      for (int dt = 0; dt < 4; ++dt) {
        const int d = dt * 16 + r;
        const int byte = (d * 128 + (kh * 32 + g * 8) * 2) ^ ((d & 7) << 4);
        bf16x8 bvr = *(const bf16x8*)(vr_l + byte);
        bf16x8 bvi = *(const bf16x8*)(vi_l + byte);
#pragma unroll
        for (int qt = 0; qt < 2; ++qt) {
          o_r[qt][dt] = __builtin_amdgcn_mfma_f32_16x16x32_bf16(af[qt], bvr, o_r[qt][dt], 0, 0, 0);
          o_i[qt][dt] = __builtin_amdgcn_mfma_f32_16x16x32_bf16(af[qt], bvi, o_i[qt][dt], 0, 0, 0);
        }
      }
    }
  }

  // Epilogue: scale by 1/rowsum of the OUTPUT row (q = q0w + qt*16 + g*4 + i).
#pragma unroll
  for (int qt = 0; qt < 2; ++qt)
#pragma unroll
    for (int i = 0; i < 4; ++i) {
      const size_t q = q0w + qt * 16 + g * 4 + i;
      const float iv = 1.0f / rowsum[(size_t)bh * kL + q];
#pragma unroll
      for (int dt = 0; dt < 4; ++dt) {
        const int d = dt * 16 + r;
        float2 val;
        val.x = o_r[qt][dt][i] * iv;
        val.y = o_i[qt][dt][i] * iv;
        *(float2*)(out + (((size_t)bh * kL + q) * kD + d) * 2) = val;
      }
    }
}

extern "C" void kernel_launch(void* const* d_in, const int* in_sizes, int n_in,
                              void* d_out, int out_size, void* d_ws, size_t ws_size,
                              hipStream_t stream) {
  const float* qr = (const float*)d_in[0];
  const float* qi = (const float*)d_in[1];
  const float* kr = (const float*)d_in[2];
  const float* ki = (const float*)d_in[3];
  const float* vr = (const float*)d_in[4];
  const float* vi = (const float*)d_in[5];
  float* out  = (float*)d_out;
  float* attn = out + kAttnOff;

  float* rowsum = (float*)d_ws;                       // 64*2048 f32 = 512 KB
  const size_t rowsum_bytes = (size_t)kBH * kL * 4;
  __hip_bfloat16* ews = (__hip_bfloat16*)((char*)d_ws + rowsum_bytes);
  const size_t e_bytes = (size_t)kBH * kL * kL * 2;   // 536.9 MB

  const bool use_ws = (ws_size >= rowsum_bytes + e_bytes);

  dim3 gridA(kL / 256, kBH);
  dim3 gridB(kL / 128, kBH);
  if (use_ws) {
    qk_exp_kernel<1><<<gridA, 256, 0, stream>>>(qr, qi, kr, ki, ews, attn, rowsum);
    pv_kernel<1><<<gridB, 256, 0, stream>>>(vr, vi, ews, attn, rowsum, out);
  } else {
    qk_exp_kernel<0><<<gridA, 256, 0, stream>>>(qr, qi, kr, ki, ews, attn, rowsum);
    pv_kernel<0><<<gridB, 256, 0, stream>>>(vr, vi, ews, attn, rowsum, out);
  }
}